// Round 11
// baseline (281.305 us; speedup 1.0000x reference)
//
#include <hip/hip_runtime.h>
#include <stdint.h>

// PointNet SA via MFMA, v8 = v7 with the stage-1 weight hoist passed BY VALUE
// (v7 passed a pointer to a local array -> address-taken -> scratch -> 450MB
// of spill traffic). Pipelined tiles via global_load_lds, raw lgkm barriers.

#define AS1 __attribute__((address_space(1)))
#define AS3 __attribute__((address_space(3)))

namespace {
constexpr int kB = 4, kN = 16384, kC = 103, kP = 2048, kS = 32;
constexpr int TPB = 4;

using short8 = __attribute__((ext_vector_type(8))) short;
using short4 = __attribute__((ext_vector_type(4))) short;
using f32x4  = __attribute__((ext_vector_type(4))) float;

constexpr int WG_HI = 0,     WG_LO = 8192;     // 64 x 128
constexpr int W1_HI = 16384, W1_LO = 20480;    // 64 x 64
constexpr int W2_HI = 24576, W2_LO = 32768;    // 128 x 64
constexpr int W3_HI = 40960, W3_LO = 73728;    // 256 x 128
constexpr size_t FT_OFF    = 262144;
constexpr size_t FT_SHORTS = (size_t)kB * kN * 128;
constexpr size_t WS_NEED   = FT_OFF + 2 * FT_SHORTS * 2;

__device__ __forceinline__ unsigned short f2bf(float x) {
    unsigned u = __float_as_uint(x);
    u += 0x7fffu + ((u >> 16) & 1u);           // RNE
    return (unsigned short)(u >> 16);
}
__device__ __forceinline__ float bf2f(unsigned short h) {
    return __uint_as_float((unsigned)h << 16);
}

__device__ __forceinline__ void glds16(const short* g, short* l) {
    __builtin_amdgcn_global_load_lds((const AS1 unsigned int*)g, (AS3 unsigned int*)l, 16, 0, 0);
}
__device__ __forceinline__ void wg_barrier() {
    asm volatile("s_waitcnt lgkmcnt(0)" ::: "memory");
    __builtin_amdgcn_s_barrier();
}

__global__ void copy_newxyz(const float* __restrict__ src, float* __restrict__ dst, int n) {
    int i = blockIdx.x * blockDim.x + threadIdx.x;
    if (i < n) dst[i] = src[i];
}

__global__ void prep_weights(const float* __restrict__ Wg, const float* __restrict__ W1,
                             const float* __restrict__ W2, const float* __restrict__ W3,
                             short* __restrict__ ws) {
    int i = blockIdx.x * blockDim.x + threadIdx.x;
    if (i >= 53248) return;
    float w; int hi, lo, j;
    if (i < 8192)       { j = i;         int o = j >> 7, c = j & 127; w = (c < 106) ? Wg[o * 106 + c] : 0.f; hi = WG_HI; lo = WG_LO; }
    else if (i < 12288) { j = i - 8192;  int o = j >> 6, c = j & 63;  w = W1[o * 64 + c];  hi = W1_HI; lo = W1_LO; }
    else if (i < 20480) { j = i - 12288; int o = j >> 6, c = j & 63;  w = W2[o * 64 + c];  hi = W2_HI; lo = W2_LO; }
    else                { j = i - 20480; int o = j >> 7, c = j & 127; w = W3[o * 128 + c]; hi = W3_HI; lo = W3_LO; }
    unsigned short h = f2bf(w);
    ws[hi + j] = (short)h;
    ws[lo + j] = (short)f2bf(w - bf2f(h));
}

__global__ __launch_bounds__(512) void prep_feat(const float* __restrict__ f,
                                                 short* __restrict__ ftH, short* __restrict__ ftL) {
    __shared__ float tile[kC][65];
    const int bb = blockIdx.x >> 8;
    const int n0 = (blockIdx.x & 255) * 64;
    const int tid = threadIdx.x;
    for (int c = tid >> 6; c < kC; c += 8)
        tile[c][tid & 63] = f[((size_t)bb * kC + c) * kN + n0 + (tid & 63)];
    __syncthreads();
    const int np = tid >> 3, gc = tid & 7;
    short* rH = ftH + ((size_t)bb * kN + n0 + np) * 128;
    short* rL = ftL + ((size_t)bb * kN + n0 + np) * 128;
    #pragma unroll
    for (int kk = 0; kk < 2; ++kk) {
        const int chunk = gc + 8 * kk;
        union { uint4 u; short s[8]; } H, L;
        #pragma unroll
        for (int e = 0; e < 8; ++e) {
            const int col = chunk * 8 + e;
            float v = (col >= 3 && col < 106) ? tile[col - 3][np] : 0.f;
            unsigned short hh = f2bf(v);
            H.s[e] = (short)hh;
            L.s[e] = (short)f2bf(v - bf2f(hh));
        }
        *(uint4*)(rH + chunk * 8) = H.u;
        *(uint4*)(rL + chunk * 8) = L.u;
    }
}

// A: m=lane&15 (W row), k=8*(lane>>4)+j; B: n=lane&15 (point), same k; D: n=lane&15, m=4*(lane>>4)+r
template<int NOT, int NPT, int KT, int LDC>
__device__ __forceinline__ void gemm_stage(
    const short* __restrict__ xh, const short* __restrict__ xl,
    const short* __restrict__ wh, const short* __restrict__ wl,
    const float* __restrict__ bias,
    int ot0, int pt0t, int lane, f32x4 (&acc)[NOT][NPT])
{
    const int q = lane >> 4, n16 = lane & 15;
    #pragma unroll
    for (int i = 0; i < NOT; ++i) {
        const f32x4 binit = *(const f32x4*)(bias + (ot0 + i) * 16 + 4 * q);
        #pragma unroll
        for (int j = 0; j < NPT; ++j) acc[i][j] = binit;
    }
    #pragma unroll
    for (int kt = 0; kt < KT; ++kt) {
        const int k0 = kt * 32 + q * 8;
        short8 bh[NPT], bl[NPT];
        #pragma unroll
        for (int j = 0; j < NPT; ++j) {
            const int p = (pt0t + j) * 16 + n16;
            const int e = p * LDC + (k0 ^ ((p & 7) << 3));
            bh[j] = *(const short8*)(xh + e);
            bl[j] = *(const short8*)(xl + e);
        }
        #pragma unroll
        for (int i = 0; i < NOT; ++i) {
            const size_t we = (size_t)((ot0 + i) * 16 + n16) * (KT * 32) + k0;
            const short8 ah = *(const short8*)(wh + we);
            const short8 al = *(const short8*)(wl + we);
            #pragma unroll
            for (int j = 0; j < NPT; ++j) {
                acc[i][j] = __builtin_amdgcn_mfma_f32_16x16x32_bf16(ah, bh[j], acc[i][j], 0, 0, 0);
                acc[i][j] = __builtin_amdgcn_mfma_f32_16x16x32_bf16(ah, bl[j], acc[i][j], 0, 0, 0);
                acc[i][j] = __builtin_amdgcn_mfma_f32_16x16x32_bf16(al, bh[j], acc[i][j], 0, 0, 0);
            }
        }
    }
}

// Stage-1 with weights passed BY VALUE (registers; nothing address-taken). KT=2.
template<int NPT, int LDC>
__device__ __forceinline__ void gemm_pre2(
    const short* __restrict__ xh, const short* __restrict__ xl,
    short8 ah0, short8 ah1, short8 al0, short8 al1,
    const float* __restrict__ bias,
    int ot0, int pt0t, int lane, f32x4 (&acc)[1][NPT])
{
    const int q = lane >> 4, n16 = lane & 15;
    const f32x4 binit = *(const f32x4*)(bias + ot0 * 16 + 4 * q);
    #pragma unroll
    for (int j = 0; j < NPT; ++j) acc[0][j] = binit;
    #pragma unroll
    for (int kt = 0; kt < 2; ++kt) {
        const short8 ah = kt ? ah1 : ah0;
        const short8 al = kt ? al1 : al0;
        const int k0 = kt * 32 + q * 8;
        short8 bh[NPT], bl[NPT];
        #pragma unroll
        for (int j = 0; j < NPT; ++j) {
            const int p = (pt0t + j) * 16 + n16;
            const int e = p * LDC + (k0 ^ ((p & 7) << 3));
            bh[j] = *(const short8*)(xh + e);
            bl[j] = *(const short8*)(xl + e);
        }
        #pragma unroll
        for (int j = 0; j < NPT; ++j) {
            acc[0][j] = __builtin_amdgcn_mfma_f32_16x16x32_bf16(ah, bh[j], acc[0][j], 0, 0, 0);
            acc[0][j] = __builtin_amdgcn_mfma_f32_16x16x32_bf16(ah, bl[j], acc[0][j], 0, 0, 0);
            acc[0][j] = __builtin_amdgcn_mfma_f32_16x16x32_bf16(al, bh[j], acc[0][j], 0, 0, 0);
        }
    }
}

template<int NOT, int NPT, bool GATE, int LDCO>
__device__ __forceinline__ void store_act(
    f32x4 (&acc)[NOT][NPT], short* __restrict__ oh, short* __restrict__ ol,
    const short* __restrict__ nfh, const short* __restrict__ nfl,
    int ot0, int pt0t, int lane)
{
    const int q = lane >> 4, n16 = lane & 15;
    #pragma unroll
    for (int i = 0; i < NOT; ++i) {
        const int ob = (ot0 + i) * 16 + 4 * q;
        #pragma unroll
        for (int j = 0; j < NPT; ++j) {
            const int p = (pt0t + j) * 16 + n16;
            const int cs = ob ^ ((p & 7) << 3);
            float v[4];
            #pragma unroll
            for (int r = 0; r < 4; ++r) v[r] = acc[i][j][r];
            if (GATE) {
                const short4 h4 = *(const short4*)(nfh + p * 128 + cs);
                const short4 l4 = *(const short4*)(nfl + p * 128 + cs);
                #pragma unroll
                for (int r = 0; r < 4; ++r) {
                    const float base = bf2f((unsigned short)h4[r]) + bf2f((unsigned short)l4[r]);
                    v[r] = fmaf(base, v[r], base);
                }
            } else {
                #pragma unroll
                for (int r = 0; r < 4; ++r) v[r] = fmaxf(v[r], 0.f);
            }
            short4 h4o, l4o;
            #pragma unroll
            for (int r = 0; r < 4; ++r) {
                const unsigned short h = f2bf(v[r]);
                h4o[r] = (short)h;
                l4o[r] = (short)f2bf(v[r] - bf2f(h));
            }
            *(short4*)(oh + p * LDCO + cs) = h4o;
            *(short4*)(ol + p * LDCO + cs) = l4o;
        }
    }
}

// ---------------- pipelined dense kernel ----------------
__global__ __launch_bounds__(512, 4) void pointnet_sa_pipe(
    const float* __restrict__ xyz, const float* __restrict__ new_xyz,
    const int* __restrict__ idx,
    const short* __restrict__ ws, const short* __restrict__ ftH, const short* __restrict__ ftL,
    const float* __restrict__ bg, const float* __restrict__ b1,
    const float* __restrict__ b2, const float* __restrict__ b3,
    float* __restrict__ out_pooled)
{
    __shared__ alignas(16) short smem[32768];     // 64 KB
    __shared__ alignas(16) float biasL[512];      // +2 KB
    short* NFh = smem;          short* NFl = smem + 8192;    // [64][128]
    short* X0h = smem + 16384;  short* X0l = smem + 20480;   // [64][64]
    short* X1h = smem + 24576;  short* X1l = smem + 28672;   // [64][64]
    short* X2h = smem + 16384;  short* X2l = smem + 24576;   // [64][128] alias X0|X1

    const int tid = threadIdx.x, lane = tid & 63, wave = tid >> 6;
    const int q = lane >> 4, n16 = lane & 15;
    const int base = blockIdx.x * (64 * TPB);
    const int b = base >> 16;
    const size_t fb = (size_t)b * kN * 128;

    // biases -> LDS
    biasL[tid] = (tid < 64) ? bg[tid] : (tid < 128) ? b1[tid - 64]
               : (tid < 256) ? b2[tid - 128] : b3[tid - 256];

    // hoist stage-1 weights into SSA values (BY VALUE everywhere; no address taken)
    const int w1row = (wave & 3) * 16 + n16;
    const short8 w1h_0 = *(const short8*)(ws + W1_HI + w1row * 64 + 0 * 32 + q * 8);
    const short8 w1h_1 = *(const short8*)(ws + W1_HI + w1row * 64 + 1 * 32 + q * 8);
    const short8 w1l_0 = *(const short8*)(ws + W1_LO + w1row * 64 + 0 * 32 + q * 8);
    const short8 w1l_1 = *(const short8*)(ws + W1_LO + w1row * 64 + 1 * 32 + q * 8);

    // ---- prologue: prefetch tile 0 ----
    {
        const int r0 = wave * 8 + (lane >> 4);
        const int n0 = idx[base + r0];
        const int n1 = idx[base + r0 + 4];
        const int c0 = ((lane & 15) ^ (lane >> 4)) * 8;
        const int c1 = ((lane & 15) ^ (4 + (lane >> 4))) * 8;
        const int l0 = __builtin_amdgcn_readfirstlane(wave * 1024);
        glds16(ftH + fb + (size_t)n0 * 128 + c0, smem + l0);
        glds16(ftH + fb + (size_t)n1 * 128 + c1, smem + l0 + 512);
        glds16(ftL + fb + (size_t)n0 * 128 + c0, smem + 8192 + l0);
        glds16(ftL + fb + (size_t)n1 * 128 + c1, smem + 8192 + l0 + 512);
    }
    float xr0 = 0, xr1 = 0, xr2 = 0, nx0 = 0, nx1 = 0, nx2 = 0;
    if ((lane & 7) == 0) {
        const int p = wave * 8 + (lane >> 3);
        const int n = idx[base + p];
        const float* xp = xyz + ((size_t)b * kN + n) * 3;
        const int pp = ((base + p) >> 5) & (kP - 1);
        const float* np = new_xyz + ((size_t)b * kP + pp) * 3;
        xr0 = xp[0]; xr1 = xp[1]; xr2 = xp[2];
        nx0 = np[0]; nx1 = np[1]; nx2 = np[2];
    }
    __syncthreads();   // drains vmcnt (tile-0 DMA + xyz) and publishes biasL
    if ((lane & 7) == 0) {
        const int p = wave * 8 + (lane >> 3);
        const int o = p * 128 + (p & 7) * 8;
        float xd[3] = { xr0 - nx0, xr1 - nx1, xr2 - nx2 };
        #pragma unroll
        for (int c = 0; c < 3; ++c) {
            const unsigned short h = f2bf(xd[c]);
            NFh[o + c] = (short)h;
            NFl[o + c] = (short)f2bf(xd[c] - bf2f(h));
        }
    }
    wg_barrier();

    for (int t = 0; t < TPB; ++t) {
        const int tb = base + t * 64;
        int ni0 = 0, ni1 = 0, nxy = 0;
        if (t + 1 < TPB) {
            const int r0 = wave * 8 + (lane >> 4);
            ni0 = idx[tb + 64 + r0];
            ni1 = idx[tb + 64 + r0 + 4];
            if ((lane & 7) == 0) nxy = idx[tb + 64 + wave * 8 + (lane >> 3)];
        }

        // ---- stage g ----
        {
            f32x4 a0[1][2];
            gemm_stage<1, 2, 4, 128>(NFh, NFl, ws + WG_HI, ws + WG_LO, biasL,
                                     wave & 3, 2 * (wave >> 2), lane, a0);
            store_act<1, 2, true, 64>(a0, X0h, X0l, NFh, NFl, wave & 3, 2 * (wave >> 2), lane);
        }
        wg_barrier();                               // B1: NF dead

        // ---- issue async prefetch of tile t+1 into NF ----
        if (t + 1 < TPB) {
            const int c0 = ((lane & 15) ^ (lane >> 4)) * 8;
            const int c1 = ((lane & 15) ^ (4 + (lane >> 4))) * 8;
            const int l0 = __builtin_amdgcn_readfirstlane(wave * 1024);
            glds16(ftH + fb + (size_t)ni0 * 128 + c0, smem + l0);
            glds16(ftH + fb + (size_t)ni1 * 128 + c1, smem + l0 + 512);
            glds16(ftL + fb + (size_t)ni0 * 128 + c0, smem + 8192 + l0);
            glds16(ftL + fb + (size_t)ni1 * 128 + c1, smem + 8192 + l0 + 512);
            if ((lane & 7) == 0) {
                const int p = wave * 8 + (lane >> 3);
                const float* xp = xyz + ((size_t)b * kN + nxy) * 3;
                const int pp = ((tb + 64 + p) >> 5) & (kP - 1);
                const float* np = new_xyz + ((size_t)b * kP + pp) * 3;
                xr0 = xp[0]; xr1 = xp[1]; xr2 = xp[2];
                nx0 = np[0]; nx1 = np[1]; nx2 = np[2];
            }
        }

        // ---- stage 1 (weights in regs by value, bias in LDS) ----
        {
            f32x4 a1[1][2];
            gemm_pre2<2, 64>(X0h, X0l, w1h_0, w1h_1, w1l_0, w1l_1, biasL + 64,
                             wave & 3, 2 * (wave >> 2), lane, a1);
            store_act<1, 2, false, 64>(a1, X1h, X1l, nullptr, nullptr,
                                       wave & 3, 2 * (wave >> 2), lane);
        }
        wg_barrier();                               // B2

        // ---- stage 2 ----
        f32x4 a2[2][2];
        gemm_stage<2, 2, 2, 64>(X1h, X1l, ws + W2_HI, ws + W2_LO, biasL + 128,
                                2 * (wave & 3), 2 * (wave >> 2), lane, a2);
        wg_barrier();                               // B3: X1 reads done
        store_act<2, 2, false, 128>(a2, X2h, X2l, nullptr, nullptr,
                                    2 * (wave & 3), 2 * (wave >> 2), lane);
        wg_barrier();                               // B3b: X2 published

        // ---- stage 3 + pool ----
        {
            f32x4 a3[2][4];
            gemm_stage<2, 4, 4, 128>(X2h, X2l, ws + W3_HI, ws + W3_LO, biasL + 256,
                                     2 * wave, 0, lane, a3);
            #pragma unroll
            for (int i = 0; i < 2; ++i)
                #pragma unroll
                for (int sg = 0; sg < 2; ++sg)
                    #pragma unroll
                    for (int r = 0; r < 4; ++r) {
                        float a = fmaxf(a3[i][2 * sg][r], a3[i][2 * sg + 1][r]);
                        a = fmaxf(a, __shfl_xor(a, 1, 16));
                        a = fmaxf(a, __shfl_xor(a, 2, 16));
                        a = fmaxf(a, __shfl_xor(a, 4, 16));
                        a = fmaxf(a, __shfl_xor(a, 8, 16));
                        a = fmaxf(a, 0.f);
                        if (n16 == 0) {
                            const int o = (2 * wave + i) * 16 + 4 * q + r;
                            const int g = (tb >> 5) + sg;
                            out_pooled[((size_t)(g >> 11) * 256 + o) * kP + (g & (kP - 1))] = a;
                        }
                    }
        }

        // ---- tile boundary: land prefetch, write xyz cols, publish ----
        if (t + 1 < TPB) {
            asm volatile("s_waitcnt vmcnt(0)" ::: "memory");
            if ((lane & 7) == 0) {
                const int p = wave * 8 + (lane >> 3);
                const int o = p * 128 + (p & 7) * 8;
                float xd[3] = { xr0 - nx0, xr1 - nx1, xr2 - nx2 };
                #pragma unroll
                for (int c = 0; c < 3; ++c) {
                    const unsigned short h = f2bf(xd[c]);
                    NFh[o + c] = (short)h;
                    NFl[o + c] = (short)f2bf(xd[c] - bf2f(h));
                }
            }
            wg_barrier();                           // B5: NF ready; X2 reads done
        }
    }
}

// ---------------- scalar fallback (v6 false-path) ----------------
__global__ __launch_bounds__(512, 4) void pointnet_sa_scalar(
    const float* __restrict__ xyz, const float* __restrict__ features,
    const float* __restrict__ new_xyz, const int* __restrict__ idx,
    const short* __restrict__ ws,
    const float* __restrict__ bg, const float* __restrict__ b1,
    const float* __restrict__ b2, const float* __restrict__ b3,
    float* __restrict__ out_pooled)
{
    __shared__ alignas(16) short smem[32768];
    short* NFh = smem;          short* NFl = smem + 8192;
    short* X0h = smem + 16384;  short* X0l = smem + 20480;
    short* X1h = smem + 24576;  short* X1l = smem + 28672;
    short* X2h = NFh;           short* X2l = NFl;

    const int tid = threadIdx.x, lane = tid & 63, wave = tid >> 6;
    const int q = lane >> 4, n16 = lane & 15;
    const int pt0 = blockIdx.x * 64;
    const int b = pt0 >> 16;

    {
        const int p = tid & 63;
        const int cg = tid >> 6;
        const int pt = pt0 + p;
        const int n = idx[pt];
        const int pp = (pt >> 5) & (kP - 1);
        const float* fbp = features + (size_t)b * kC * kN + n;
        const float* xp = xyz + ((size_t)b * kN + n) * 3;
        const float* np = new_xyz + ((size_t)b * kP + pp) * 3;
        for (int c = cg; c < 128; c += 8) {
            float v;
            if (c < 3)        v = xp[c] - np[c];
            else if (c < 106) v = fbp[(size_t)(c - 3) * kN];
            else              v = 0.f;
            const unsigned short h = f2bf(v);
            const int cs = c ^ ((p & 7) << 3);
            NFh[p * 128 + cs] = (short)h;
            NFl[p * 128 + cs] = (short)f2bf(v - bf2f(h));
        }
    }
    __syncthreads();
    {
        f32x4 acc[1][2];
        gemm_stage<1, 2, 4, 128>(NFh, NFl, ws + WG_HI, ws + WG_LO, bg,
                                 wave & 3, 2 * (wave >> 2), lane, acc);
        store_act<1, 2, true, 64>(acc, X0h, X0l, NFh, NFl, wave & 3, 2 * (wave >> 2), lane);
    }
    __syncthreads();
    {
        f32x4 acc[1][2];
        gemm_stage<1, 2, 2, 64>(X0h, X0l, ws + W1_HI, ws + W1_LO, b1,
                                wave & 3, 2 * (wave >> 2), lane, acc);
        store_act<1, 2, false, 64>(acc, X1h, X1l, nullptr, nullptr, wave & 3, 2 * (wave >> 2), lane);
    }
    __syncthreads();
    {
        f32x4 acc[2][2];
        gemm_stage<2, 2, 2, 64>(X1h, X1l, ws + W2_HI, ws + W2_LO, b2,
                                2 * (wave & 3), 2 * (wave >> 2), lane, acc);
        store_act<2, 2, false, 128>(acc, X2h, X2l, nullptr, nullptr, 2 * (wave & 3), 2 * (wave >> 2), lane);
    }
    __syncthreads();
    {
        f32x4 acc[2][4];
        gemm_stage<2, 4, 4, 128>(X2h, X2l, ws + W3_HI, ws + W3_LO, b3,
                                 2 * wave, 0, lane, acc);
        #pragma unroll
        for (int i = 0; i < 2; ++i)
            #pragma unroll
            for (int sg = 0; sg < 2; ++sg)
                #pragma unroll
                for (int r = 0; r < 4; ++r) {
                    float a = fmaxf(acc[i][2 * sg][r], acc[i][2 * sg + 1][r]);
                    a = fmaxf(a, __shfl_xor(a, 1, 16));
                    a = fmaxf(a, __shfl_xor(a, 2, 16));
                    a = fmaxf(a, __shfl_xor(a, 4, 16));
                    a = fmaxf(a, __shfl_xor(a, 8, 16));
                    a = fmaxf(a, 0.f);
                    if (n16 == 0) {
                        const int o = (2 * wave + i) * 16 + 4 * q + r;
                        const int g = (pt0 >> 5) + sg;
                        out_pooled[((size_t)(g >> 11) * 256 + o) * kP + (g & (kP - 1))] = a;
                    }
                }
    }
}
}  // namespace

extern "C" void kernel_launch(void* const* d_in, const int* in_sizes, int n_in,
                              void* d_out, int out_size, void* d_ws, size_t ws_size,
                              hipStream_t stream) {
    const float* xyz      = (const float*)d_in[0];
    const float* features = (const float*)d_in[1];
    const float* new_xyz  = (const float*)d_in[2];
    const int*   idx      = (const int*)d_in[3];
    const float* Wg = (const float*)d_in[4];
    const float* bg = (const float*)d_in[5];
    const float* W1 = (const float*)d_in[6];
    const float* b1 = (const float*)d_in[7];
    const float* W2 = (const float*)d_in[8];
    const float* b2 = (const float*)d_in[9];
    const float* W3 = (const float*)d_in[10];
    const float* b3 = (const float*)d_in[11];
    float* out = (float*)d_out;
    short* ws  = (short*)d_ws;
    short* ftH = (short*)((char*)d_ws + FT_OFF);
    short* ftL = ftH + FT_SHORTS;

    const int nxyz = kB * kP * 3;
    copy_newxyz<<<(nxyz + 255) / 256, 256, 0, stream>>>(new_xyz, out, nxyz);
    prep_weights<<<(53248 + 255) / 256, 256, 0, stream>>>(Wg, W1, W2, W3, ws);

    float* pooled = out + nxyz;
    if (ws_size >= WS_NEED) {
        prep_feat<<<kB * (kN / 64), 512, 0, stream>>>(features, ftH, ftL);
        pointnet_sa_pipe<<<(kB * kP * kS) / 64 / TPB, 512, 0, stream>>>(
            xyz, new_xyz, idx, ws, ftH, ftL, bg, b1, b2, b3, pooled);
    } else {
        pointnet_sa_scalar<<<(kB * kP * kS) / 64, 512, 0, stream>>>(
            xyz, features, new_xyz, idx, ws, bg, b1, b2, b3, pooled);
    }
}

// Round 12
// 217.075 us; speedup vs baseline: 1.2959x; 1.2959x over previous
//
#include <hip/hip_runtime.h>
#include <stdint.h>

// PointNet SA via MFMA, v9 = v8 with __launch_bounds__(512, 2) on the pipe kernel.
// ROOT CAUSE of v7/v8's 450MB/270MB scratch traffic: __launch_bounds__(512,4)
// imposed a 64-VGPR cap (4 blk/CU x 8 waves = 8 waves/SIMD -> 64 VGPR), forcing
// ~36 regs/thread of spills. LDS (66KB) caps at 2 blocks/CU anyway, so declare 2.

#define AS1 __attribute__((address_space(1)))
#define AS3 __attribute__((address_space(3)))

namespace {
constexpr int kB = 4, kN = 16384, kC = 103, kP = 2048, kS = 32;
constexpr int TPB = 4;

using short8 = __attribute__((ext_vector_type(8))) short;
using short4 = __attribute__((ext_vector_type(4))) short;
using f32x4  = __attribute__((ext_vector_type(4))) float;

constexpr int WG_HI = 0,     WG_LO = 8192;     // 64 x 128
constexpr int W1_HI = 16384, W1_LO = 20480;    // 64 x 64
constexpr int W2_HI = 24576, W2_LO = 32768;    // 128 x 64
constexpr int W3_HI = 40960, W3_LO = 73728;    // 256 x 128
constexpr size_t FT_OFF    = 262144;
constexpr size_t FT_SHORTS = (size_t)kB * kN * 128;
constexpr size_t WS_NEED   = FT_OFF + 2 * FT_SHORTS * 2;

__device__ __forceinline__ unsigned short f2bf(float x) {
    unsigned u = __float_as_uint(x);
    u += 0x7fffu + ((u >> 16) & 1u);           // RNE
    return (unsigned short)(u >> 16);
}
__device__ __forceinline__ float bf2f(unsigned short h) {
    return __uint_as_float((unsigned)h << 16);
}

__device__ __forceinline__ void glds16(const short* g, short* l) {
    __builtin_amdgcn_global_load_lds((const AS1 unsigned int*)g, (AS3 unsigned int*)l, 16, 0, 0);
}
__device__ __forceinline__ void wg_barrier() {
    asm volatile("s_waitcnt lgkmcnt(0)" ::: "memory");
    __builtin_amdgcn_s_barrier();
}

__global__ void copy_newxyz(const float* __restrict__ src, float* __restrict__ dst, int n) {
    int i = blockIdx.x * blockDim.x + threadIdx.x;
    if (i < n) dst[i] = src[i];
}

__global__ void prep_weights(const float* __restrict__ Wg, const float* __restrict__ W1,
                             const float* __restrict__ W2, const float* __restrict__ W3,
                             short* __restrict__ ws) {
    int i = blockIdx.x * blockDim.x + threadIdx.x;
    if (i >= 53248) return;
    float w; int hi, lo, j;
    if (i < 8192)       { j = i;         int o = j >> 7, c = j & 127; w = (c < 106) ? Wg[o * 106 + c] : 0.f; hi = WG_HI; lo = WG_LO; }
    else if (i < 12288) { j = i - 8192;  int o = j >> 6, c = j & 63;  w = W1[o * 64 + c];  hi = W1_HI; lo = W1_LO; }
    else if (i < 20480) { j = i - 12288; int o = j >> 6, c = j & 63;  w = W2[o * 64 + c];  hi = W2_HI; lo = W2_LO; }
    else                { j = i - 20480; int o = j >> 7, c = j & 127; w = W3[o * 128 + c]; hi = W3_HI; lo = W3_LO; }
    unsigned short h = f2bf(w);
    ws[hi + j] = (short)h;
    ws[lo + j] = (short)f2bf(w - bf2f(h));
}

__global__ __launch_bounds__(512) void prep_feat(const float* __restrict__ f,
                                                 short* __restrict__ ftH, short* __restrict__ ftL) {
    __shared__ float tile[kC][65];
    const int bb = blockIdx.x >> 8;
    const int n0 = (blockIdx.x & 255) * 64;
    const int tid = threadIdx.x;
    for (int c = tid >> 6; c < kC; c += 8)
        tile[c][tid & 63] = f[((size_t)bb * kC + c) * kN + n0 + (tid & 63)];
    __syncthreads();
    const int np = tid >> 3, gc = tid & 7;
    short* rH = ftH + ((size_t)bb * kN + n0 + np) * 128;
    short* rL = ftL + ((size_t)bb * kN + n0 + np) * 128;
    #pragma unroll
    for (int kk = 0; kk < 2; ++kk) {
        const int chunk = gc + 8 * kk;
        union { uint4 u; short s[8]; } H, L;
        #pragma unroll
        for (int e = 0; e < 8; ++e) {
            const int col = chunk * 8 + e;
            float v = (col >= 3 && col < 106) ? tile[col - 3][np] : 0.f;
            unsigned short hh = f2bf(v);
            H.s[e] = (short)hh;
            L.s[e] = (short)f2bf(v - bf2f(hh));
        }
        *(uint4*)(rH + chunk * 8) = H.u;
        *(uint4*)(rL + chunk * 8) = L.u;
    }
}

// A: m=lane&15 (W row), k=8*(lane>>4)+j; B: n=lane&15 (point), same k; D: n=lane&15, m=4*(lane>>4)+r
template<int NOT, int NPT, int KT, int LDC>
__device__ __forceinline__ void gemm_stage(
    const short* __restrict__ xh, const short* __restrict__ xl,
    const short* __restrict__ wh, const short* __restrict__ wl,
    const float* __restrict__ bias,
    int ot0, int pt0t, int lane, f32x4 (&acc)[NOT][NPT])
{
    const int q = lane >> 4, n16 = lane & 15;
    #pragma unroll
    for (int i = 0; i < NOT; ++i) {
        const f32x4 binit = *(const f32x4*)(bias + (ot0 + i) * 16 + 4 * q);
        #pragma unroll
        for (int j = 0; j < NPT; ++j) acc[i][j] = binit;
    }
    #pragma unroll
    for (int kt = 0; kt < KT; ++kt) {
        const int k0 = kt * 32 + q * 8;
        short8 bh[NPT], bl[NPT];
        #pragma unroll
        for (int j = 0; j < NPT; ++j) {
            const int p = (pt0t + j) * 16 + n16;
            const int e = p * LDC + (k0 ^ ((p & 7) << 3));
            bh[j] = *(const short8*)(xh + e);
            bl[j] = *(const short8*)(xl + e);
        }
        #pragma unroll
        for (int i = 0; i < NOT; ++i) {
            const size_t we = (size_t)((ot0 + i) * 16 + n16) * (KT * 32) + k0;
            const short8 ah = *(const short8*)(wh + we);
            const short8 al = *(const short8*)(wl + we);
            #pragma unroll
            for (int j = 0; j < NPT; ++j) {
                acc[i][j] = __builtin_amdgcn_mfma_f32_16x16x32_bf16(ah, bh[j], acc[i][j], 0, 0, 0);
                acc[i][j] = __builtin_amdgcn_mfma_f32_16x16x32_bf16(ah, bl[j], acc[i][j], 0, 0, 0);
                acc[i][j] = __builtin_amdgcn_mfma_f32_16x16x32_bf16(al, bh[j], acc[i][j], 0, 0, 0);
            }
        }
    }
}

// Stage-1 with weights passed BY VALUE (registers; nothing address-taken). KT=2.
template<int NPT, int LDC>
__device__ __forceinline__ void gemm_pre2(
    const short* __restrict__ xh, const short* __restrict__ xl,
    short8 ah0, short8 ah1, short8 al0, short8 al1,
    const float* __restrict__ bias,
    int ot0, int pt0t, int lane, f32x4 (&acc)[1][NPT])
{
    const int q = lane >> 4, n16 = lane & 15;
    const f32x4 binit = *(const f32x4*)(bias + ot0 * 16 + 4 * q);
    #pragma unroll
    for (int j = 0; j < NPT; ++j) acc[0][j] = binit;
    #pragma unroll
    for (int kt = 0; kt < 2; ++kt) {
        const short8 ah = kt ? ah1 : ah0;
        const short8 al = kt ? al1 : al0;
        const int k0 = kt * 32 + q * 8;
        short8 bh[NPT], bl[NPT];
        #pragma unroll
        for (int j = 0; j < NPT; ++j) {
            const int p = (pt0t + j) * 16 + n16;
            const int e = p * LDC + (k0 ^ ((p & 7) << 3));
            bh[j] = *(const short8*)(xh + e);
            bl[j] = *(const short8*)(xl + e);
        }
        #pragma unroll
        for (int j = 0; j < NPT; ++j) {
            acc[0][j] = __builtin_amdgcn_mfma_f32_16x16x32_bf16(ah, bh[j], acc[0][j], 0, 0, 0);
            acc[0][j] = __builtin_amdgcn_mfma_f32_16x16x32_bf16(ah, bl[j], acc[0][j], 0, 0, 0);
            acc[0][j] = __builtin_amdgcn_mfma_f32_16x16x32_bf16(al, bh[j], acc[0][j], 0, 0, 0);
        }
    }
}

template<int NOT, int NPT, bool GATE, int LDCO>
__device__ __forceinline__ void store_act(
    f32x4 (&acc)[NOT][NPT], short* __restrict__ oh, short* __restrict__ ol,
    const short* __restrict__ nfh, const short* __restrict__ nfl,
    int ot0, int pt0t, int lane)
{
    const int q = lane >> 4, n16 = lane & 15;
    #pragma unroll
    for (int i = 0; i < NOT; ++i) {
        const int ob = (ot0 + i) * 16 + 4 * q;
        #pragma unroll
        for (int j = 0; j < NPT; ++j) {
            const int p = (pt0t + j) * 16 + n16;
            const int cs = ob ^ ((p & 7) << 3);
            float v[4];
            #pragma unroll
            for (int r = 0; r < 4; ++r) v[r] = acc[i][j][r];
            if (GATE) {
                const short4 h4 = *(const short4*)(nfh + p * 128 + cs);
                const short4 l4 = *(const short4*)(nfl + p * 128 + cs);
                #pragma unroll
                for (int r = 0; r < 4; ++r) {
                    const float base = bf2f((unsigned short)h4[r]) + bf2f((unsigned short)l4[r]);
                    v[r] = fmaf(base, v[r], base);
                }
            } else {
                #pragma unroll
                for (int r = 0; r < 4; ++r) v[r] = fmaxf(v[r], 0.f);
            }
            short4 h4o, l4o;
            #pragma unroll
            for (int r = 0; r < 4; ++r) {
                const unsigned short h = f2bf(v[r]);
                h4o[r] = (short)h;
                l4o[r] = (short)f2bf(v[r] - bf2f(h));
            }
            *(short4*)(oh + p * LDCO + cs) = h4o;
            *(short4*)(ol + p * LDCO + cs) = l4o;
        }
    }
}

// ---------------- pipelined dense kernel ----------------
__global__ __launch_bounds__(512, 2) void pointnet_sa_pipe(
    const float* __restrict__ xyz, const float* __restrict__ new_xyz,
    const int* __restrict__ idx,
    const short* __restrict__ ws, const short* __restrict__ ftH, const short* __restrict__ ftL,
    const float* __restrict__ bg, const float* __restrict__ b1,
    const float* __restrict__ b2, const float* __restrict__ b3,
    float* __restrict__ out_pooled)
{
    __shared__ alignas(16) short smem[32768];     // 64 KB
    __shared__ alignas(16) float biasL[512];      // +2 KB
    short* NFh = smem;          short* NFl = smem + 8192;    // [64][128]
    short* X0h = smem + 16384;  short* X0l = smem + 20480;   // [64][64]
    short* X1h = smem + 24576;  short* X1l = smem + 28672;   // [64][64]
    short* X2h = smem + 16384;  short* X2l = smem + 24576;   // [64][128] alias X0|X1

    const int tid = threadIdx.x, lane = tid & 63, wave = tid >> 6;
    const int q = lane >> 4, n16 = lane & 15;
    const int base = blockIdx.x * (64 * TPB);
    const int b = base >> 16;
    const size_t fb = (size_t)b * kN * 128;

    // biases -> LDS
    biasL[tid] = (tid < 64) ? bg[tid] : (tid < 128) ? b1[tid - 64]
               : (tid < 256) ? b2[tid - 128] : b3[tid - 256];

    // hoist stage-1 weights into SSA values (BY VALUE everywhere; no address taken)
    const int w1row = (wave & 3) * 16 + n16;
    const short8 w1h_0 = *(const short8*)(ws + W1_HI + w1row * 64 + 0 * 32 + q * 8);
    const short8 w1h_1 = *(const short8*)(ws + W1_HI + w1row * 64 + 1 * 32 + q * 8);
    const short8 w1l_0 = *(const short8*)(ws + W1_LO + w1row * 64 + 0 * 32 + q * 8);
    const short8 w1l_1 = *(const short8*)(ws + W1_LO + w1row * 64 + 1 * 32 + q * 8);

    // ---- prologue: prefetch tile 0 ----
    {
        const int r0 = wave * 8 + (lane >> 4);
        const int n0 = idx[base + r0];
        const int n1 = idx[base + r0 + 4];
        const int c0 = ((lane & 15) ^ (lane >> 4)) * 8;
        const int c1 = ((lane & 15) ^ (4 + (lane >> 4))) * 8;
        const int l0 = __builtin_amdgcn_readfirstlane(wave * 1024);
        glds16(ftH + fb + (size_t)n0 * 128 + c0, smem + l0);
        glds16(ftH + fb + (size_t)n1 * 128 + c1, smem + l0 + 512);
        glds16(ftL + fb + (size_t)n0 * 128 + c0, smem + 8192 + l0);
        glds16(ftL + fb + (size_t)n1 * 128 + c1, smem + 8192 + l0 + 512);
    }
    float xr0 = 0, xr1 = 0, xr2 = 0, nx0 = 0, nx1 = 0, nx2 = 0;
    if ((lane & 7) == 0) {
        const int p = wave * 8 + (lane >> 3);
        const int n = idx[base + p];
        const float* xp = xyz + ((size_t)b * kN + n) * 3;
        const int pp = ((base + p) >> 5) & (kP - 1);
        const float* np = new_xyz + ((size_t)b * kP + pp) * 3;
        xr0 = xp[0]; xr1 = xp[1]; xr2 = xp[2];
        nx0 = np[0]; nx1 = np[1]; nx2 = np[2];
    }
    __syncthreads();   // drains vmcnt (tile-0 DMA + xyz) and publishes biasL
    if ((lane & 7) == 0) {
        const int p = wave * 8 + (lane >> 3);
        const int o = p * 128 + (p & 7) * 8;
        float xd[3] = { xr0 - nx0, xr1 - nx1, xr2 - nx2 };
        #pragma unroll
        for (int c = 0; c < 3; ++c) {
            const unsigned short h = f2bf(xd[c]);
            NFh[o + c] = (short)h;
            NFl[o + c] = (short)f2bf(xd[c] - bf2f(h));
        }
    }
    wg_barrier();

    for (int t = 0; t < TPB; ++t) {
        const int tb = base + t * 64;
        int ni0 = 0, ni1 = 0, nxy = 0;
        if (t + 1 < TPB) {
            const int r0 = wave * 8 + (lane >> 4);
            ni0 = idx[tb + 64 + r0];
            ni1 = idx[tb + 64 + r0 + 4];
            if ((lane & 7) == 0) nxy = idx[tb + 64 + wave * 8 + (lane >> 3)];
        }

        // ---- stage g ----
        {
            f32x4 a0[1][2];
            gemm_stage<1, 2, 4, 128>(NFh, NFl, ws + WG_HI, ws + WG_LO, biasL,
                                     wave & 3, 2 * (wave >> 2), lane, a0);
            store_act<1, 2, true, 64>(a0, X0h, X0l, NFh, NFl, wave & 3, 2 * (wave >> 2), lane);
        }
        wg_barrier();                               // B1: NF dead

        // ---- issue async prefetch of tile t+1 into NF ----
        if (t + 1 < TPB) {
            const int c0 = ((lane & 15) ^ (lane >> 4)) * 8;
            const int c1 = ((lane & 15) ^ (4 + (lane >> 4))) * 8;
            const int l0 = __builtin_amdgcn_readfirstlane(wave * 1024);
            glds16(ftH + fb + (size_t)ni0 * 128 + c0, smem + l0);
            glds16(ftH + fb + (size_t)ni1 * 128 + c1, smem + l0 + 512);
            glds16(ftL + fb + (size_t)ni0 * 128 + c0, smem + 8192 + l0);
            glds16(ftL + fb + (size_t)ni1 * 128 + c1, smem + 8192 + l0 + 512);
            if ((lane & 7) == 0) {
                const int p = wave * 8 + (lane >> 3);
                const float* xp = xyz + ((size_t)b * kN + nxy) * 3;
                const int pp = ((tb + 64 + p) >> 5) & (kP - 1);
                const float* np = new_xyz + ((size_t)b * kP + pp) * 3;
                xr0 = xp[0]; xr1 = xp[1]; xr2 = xp[2];
                nx0 = np[0]; nx1 = np[1]; nx2 = np[2];
            }
        }

        // ---- stage 1 (weights in regs by value, bias in LDS) ----
        {
            f32x4 a1[1][2];
            gemm_pre2<2, 64>(X0h, X0l, w1h_0, w1h_1, w1l_0, w1l_1, biasL + 64,
                             wave & 3, 2 * (wave >> 2), lane, a1);
            store_act<1, 2, false, 64>(a1, X1h, X1l, nullptr, nullptr,
                                       wave & 3, 2 * (wave >> 2), lane);
        }
        wg_barrier();                               // B2

        // ---- stage 2 ----
        f32x4 a2[2][2];
        gemm_stage<2, 2, 2, 64>(X1h, X1l, ws + W2_HI, ws + W2_LO, biasL + 128,
                                2 * (wave & 3), 2 * (wave >> 2), lane, a2);
        wg_barrier();                               // B3: X1 reads done
        store_act<2, 2, false, 128>(a2, X2h, X2l, nullptr, nullptr,
                                    2 * (wave & 3), 2 * (wave >> 2), lane);
        wg_barrier();                               // B3b: X2 published

        // ---- stage 3 + pool ----
        {
            f32x4 a3[2][4];
            gemm_stage<2, 4, 4, 128>(X2h, X2l, ws + W3_HI, ws + W3_LO, biasL + 256,
                                     2 * wave, 0, lane, a3);
            #pragma unroll
            for (int i = 0; i < 2; ++i)
                #pragma unroll
                for (int sg = 0; sg < 2; ++sg)
                    #pragma unroll
                    for (int r = 0; r < 4; ++r) {
                        float a = fmaxf(a3[i][2 * sg][r], a3[i][2 * sg + 1][r]);
                        a = fmaxf(a, __shfl_xor(a, 1, 16));
                        a = fmaxf(a, __shfl_xor(a, 2, 16));
                        a = fmaxf(a, __shfl_xor(a, 4, 16));
                        a = fmaxf(a, __shfl_xor(a, 8, 16));
                        a = fmaxf(a, 0.f);
                        if (n16 == 0) {
                            const int o = (2 * wave + i) * 16 + 4 * q + r;
                            const int g = (tb >> 5) + sg;
                            out_pooled[((size_t)(g >> 11) * 256 + o) * kP + (g & (kP - 1))] = a;
                        }
                    }
        }

        // ---- tile boundary: land prefetch, write xyz cols, publish ----
        if (t + 1 < TPB) {
            asm volatile("s_waitcnt vmcnt(0)" ::: "memory");
            if ((lane & 7) == 0) {
                const int p = wave * 8 + (lane >> 3);
                const int o = p * 128 + (p & 7) * 8;
                float xd[3] = { xr0 - nx0, xr1 - nx1, xr2 - nx2 };
                #pragma unroll
                for (int c = 0; c < 3; ++c) {
                    const unsigned short h = f2bf(xd[c]);
                    NFh[o + c] = (short)h;
                    NFl[o + c] = (short)f2bf(xd[c] - bf2f(h));
                }
            }
            wg_barrier();                           // B5: NF ready; X2 reads done
        }
    }
}

// ---------------- scalar fallback (v6 false-path) ----------------
__global__ __launch_bounds__(512, 2) void pointnet_sa_scalar(
    const float* __restrict__ xyz, const float* __restrict__ features,
    const float* __restrict__ new_xyz, const int* __restrict__ idx,
    const short* __restrict__ ws,
    const float* __restrict__ bg, const float* __restrict__ b1,
    const float* __restrict__ b2, const float* __restrict__ b3,
    float* __restrict__ out_pooled)
{
    __shared__ alignas(16) short smem[32768];
    short* NFh = smem;          short* NFl = smem + 8192;
    short* X0h = smem + 16384;  short* X0l = smem + 20480;
    short* X1h = smem + 24576;  short* X1l = smem + 28672;
    short* X2h = NFh;           short* X2l = NFl;

    const int tid = threadIdx.x, lane = tid & 63, wave = tid >> 6;
    const int q = lane >> 4, n16 = lane & 15;
    const int pt0 = blockIdx.x * 64;
    const int b = pt0 >> 16;

    {
        const int p = tid & 63;
        const int cg = tid >> 6;
        const int pt = pt0 + p;
        const int n = idx[pt];
        const int pp = (pt >> 5) & (kP - 1);
        const float* fbp = features + (size_t)b * kC * kN + n;
        const float* xp = xyz + ((size_t)b * kN + n) * 3;
        const float* np = new_xyz + ((size_t)b * kP + pp) * 3;
        for (int c = cg; c < 128; c += 8) {
            float v;
            if (c < 3)        v = xp[c] - np[c];
            else if (c < 106) v = fbp[(size_t)(c - 3) * kN];
            else              v = 0.f;
            const unsigned short h = f2bf(v);
            const int cs = c ^ ((p & 7) << 3);
            NFh[p * 128 + cs] = (short)h;
            NFl[p * 128 + cs] = (short)f2bf(v - bf2f(h));
        }
    }
    __syncthreads();
    {
        f32x4 acc[1][2];
        gemm_stage<1, 2, 4, 128>(NFh, NFl, ws + WG_HI, ws + WG_LO, bg,
                                 wave & 3, 2 * (wave >> 2), lane, acc);
        store_act<1, 2, true, 64>(acc, X0h, X0l, NFh, NFl, wave & 3, 2 * (wave >> 2), lane);
    }
    __syncthreads();
    {
        f32x4 acc[1][2];
        gemm_stage<1, 2, 2, 64>(X0h, X0l, ws + W1_HI, ws + W1_LO, b1,
                                wave & 3, 2 * (wave >> 2), lane, acc);
        store_act<1, 2, false, 64>(acc, X1h, X1l, nullptr, nullptr, wave & 3, 2 * (wave >> 2), lane);
    }
    __syncthreads();
    {
        f32x4 acc[2][2];
        gemm_stage<2, 2, 2, 64>(X1h, X1l, ws + W2_HI, ws + W2_LO, b2,
                                2 * (wave & 3), 2 * (wave >> 2), lane, acc);
        store_act<2, 2, false, 128>(acc, X2h, X2l, nullptr, nullptr, 2 * (wave & 3), 2 * (wave >> 2), lane);
    }
    __syncthreads();
    {
        f32x4 acc[2][4];
        gemm_stage<2, 4, 4, 128>(X2h, X2l, ws + W3_HI, ws + W3_LO, b3,
                                 2 * wave, 0, lane, acc);
        #pragma unroll
        for (int i = 0; i < 2; ++i)
            #pragma unroll
            for (int sg = 0; sg < 2; ++sg)
                #pragma unroll
                for (int r = 0; r < 4; ++r) {
                    float a = fmaxf(acc[i][2 * sg][r], acc[i][2 * sg + 1][r]);
                    a = fmaxf(a, __shfl_xor(a, 1, 16));
                    a = fmaxf(a, __shfl_xor(a, 2, 16));
                    a = fmaxf(a, __shfl_xor(a, 4, 16));
                    a = fmaxf(a, __shfl_xor(a, 8, 16));
                    a = fmaxf(a, 0.f);
                    if (n16 == 0) {
                        const int o = (2 * wave + i) * 16 + 4 * q + r;
                        const int g = (pt0 >> 5) + sg;
                        out_pooled[((size_t)(g >> 11) * 256 + o) * kP + (g & (kP - 1))] = a;
                    }
                }
    }
}
}  // namespace

extern "C" void kernel_launch(void* const* d_in, const int* in_sizes, int n_in,
                              void* d_out, int out_size, void* d_ws, size_t ws_size,
                              hipStream_t stream) {
    const float* xyz      = (const float*)d_in[0];
    const float* features = (const float*)d_in[1];
    const float* new_xyz  = (const float*)d_in[2];
    const int*   idx      = (const int*)d_in[3];
    const float* Wg = (const float*)d_in[4];
    const float* bg = (const float*)d_in[5];
    const float* W1 = (const float*)d_in[6];
    const float* b1 = (const float*)d_in[7];
    const float* W2 = (const float*)d_in[8];
    const float* b2 = (const float*)d_in[9];
    const float* W3 = (const float*)d_in[10];
    const float* b3 = (const float*)d_in[11];
    float* out = (float*)d_out;
    short* ws  = (short*)d_ws;
    short* ftH = (short*)((char*)d_ws + FT_OFF);
    short* ftL = ftH + FT_SHORTS;

    const int nxyz = kB * kP * 3;
    copy_newxyz<<<(nxyz + 255) / 256, 256, 0, stream>>>(new_xyz, out, nxyz);
    prep_weights<<<(53248 + 255) / 256, 256, 0, stream>>>(Wg, W1, W2, W3, ws);

    float* pooled = out + nxyz;
    if (ws_size >= WS_NEED) {
        prep_feat<<<kB * (kN / 64), 512, 0, stream>>>(features, ftH, ftL);
        pointnet_sa_pipe<<<(kB * kP * kS) / 64 / TPB, 512, 0, stream>>>(
            xyz, new_xyz, idx, ws, ftH, ftL, bg, b1, b2, b3, pooled);
    } else {
        pointnet_sa_scalar<<<(kB * kP * kS) / 64, 512, 0, stream>>>(
            xyz, features, new_xyz, idx, ws, bg, b1, b2, b3, pooled);
    }
}

// Round 13
// 184.764 us; speedup vs baseline: 1.5225x; 1.1749x over previous
//
#include <hip/hip_runtime.h>
#include <stdint.h>

// PointNet SA via MFMA, v10 = v6 structure (1 tile/block, 4096 blocks — beat the
// pipelined v9 217us) + LDS compaction 64KB -> 48KB for 3 blocks/CU:
//   X1 lives in NF cols 0-63 (NF dead after stage g), X2 splits across the X0
//   region (cols 0-63) and NF cols 64-127. Swizzle XOR (<64) never crosses the
//   64-col boundary, so per-half write/read swizzles stay consistent.

namespace {
constexpr int kB = 4, kN = 16384, kC = 103, kP = 2048, kS = 32;

using short8 = __attribute__((ext_vector_type(8))) short;
using short4 = __attribute__((ext_vector_type(4))) short;
using f32x4  = __attribute__((ext_vector_type(4))) float;

constexpr int WG_HI = 0,     WG_LO = 8192;     // 64 x 128
constexpr int W1_HI = 16384, W1_LO = 20480;    // 64 x 64
constexpr int W2_HI = 24576, W2_LO = 32768;    // 128 x 64
constexpr int W3_HI = 40960, W3_LO = 73728;    // 256 x 128
constexpr size_t FT_OFF    = 262144;
constexpr size_t FT_SHORTS = (size_t)kB * kN * 128;
constexpr size_t WS_NEED   = FT_OFF + 2 * FT_SHORTS * 2;

__device__ __forceinline__ unsigned short f2bf(float x) {
    unsigned u = __float_as_uint(x);
    u += 0x7fffu + ((u >> 16) & 1u);           // RNE
    return (unsigned short)(u >> 16);
}
__device__ __forceinline__ float bf2f(unsigned short h) {
    return __uint_as_float((unsigned)h << 16);
}

__global__ void copy_newxyz(const float* __restrict__ src, float* __restrict__ dst, int n) {
    int i = blockIdx.x * blockDim.x + threadIdx.x;
    if (i < n) dst[i] = src[i];
}

__global__ void prep_weights(const float* __restrict__ Wg, const float* __restrict__ W1,
                             const float* __restrict__ W2, const float* __restrict__ W3,
                             short* __restrict__ ws) {
    int i = blockIdx.x * blockDim.x + threadIdx.x;
    if (i >= 53248) return;
    float w; int hi, lo, j;
    if (i < 8192)       { j = i;         int o = j >> 7, c = j & 127; w = (c < 106) ? Wg[o * 106 + c] : 0.f; hi = WG_HI; lo = WG_LO; }
    else if (i < 12288) { j = i - 8192;  int o = j >> 6, c = j & 63;  w = W1[o * 64 + c];  hi = W1_HI; lo = W1_LO; }
    else if (i < 20480) { j = i - 12288; int o = j >> 6, c = j & 63;  w = W2[o * 64 + c];  hi = W2_HI; lo = W2_LO; }
    else                { j = i - 20480; int o = j >> 7, c = j & 127; w = W3[o * 128 + c]; hi = W3_HI; lo = W3_LO; }
    unsigned short h = f2bf(w);
    ws[hi + j] = (short)h;
    ws[lo + j] = (short)f2bf(w - bf2f(h));
}

__global__ __launch_bounds__(512) void prep_feat(const float* __restrict__ f,
                                                 short* __restrict__ ftH, short* __restrict__ ftL) {
    __shared__ float tile[kC][65];
    const int bb = blockIdx.x >> 8;
    const int n0 = (blockIdx.x & 255) * 64;
    const int tid = threadIdx.x;
    for (int c = tid >> 6; c < kC; c += 8)
        tile[c][tid & 63] = f[((size_t)bb * kC + c) * kN + n0 + (tid & 63)];
    __syncthreads();
    const int np = tid >> 3, gc = tid & 7;
    short* rH = ftH + ((size_t)bb * kN + n0 + np) * 128;
    short* rL = ftL + ((size_t)bb * kN + n0 + np) * 128;
    #pragma unroll
    for (int kk = 0; kk < 2; ++kk) {
        const int chunk = gc + 8 * kk;
        union { uint4 u; short s[8]; } H, L;
        #pragma unroll
        for (int e = 0; e < 8; ++e) {
            const int col = chunk * 8 + e;
            float v = (col >= 3 && col < 106) ? tile[col - 3][np] : 0.f;
            unsigned short hh = f2bf(v);
            H.s[e] = (short)hh;
            L.s[e] = (short)f2bf(v - bf2f(hh));
        }
        *(uint4*)(rH + chunk * 8) = H.u;
        *(uint4*)(rL + chunk * 8) = L.u;
    }
}

// A: m=lane&15 (W row), k=8*(lane>>4)+j; B: n=lane&15 (point), same k; D: n=lane&15, m=4*(lane>>4)+r
// B element = x[p*LDC + ((k0) ^ ((p&7)<<3))], weight element = w[row*LDW + kwoff + k0].
template<int NOT, int NPT, int KT, int LDC, int LDW, bool INIT>
__device__ __forceinline__ void gemm_core(
    const short* __restrict__ xh, const short* __restrict__ xl,
    const short* __restrict__ wh, const short* __restrict__ wl,
    const float* __restrict__ bias, int kwoff,
    int ot0, int pt0t, int lane, f32x4 (&acc)[NOT][NPT])
{
    const int q = lane >> 4, n16 = lane & 15;
    if constexpr (INIT) {
        #pragma unroll
        for (int i = 0; i < NOT; ++i) {
            const f32x4 binit = *(const f32x4*)(bias + (ot0 + i) * 16 + 4 * q);
            #pragma unroll
            for (int j = 0; j < NPT; ++j) acc[i][j] = binit;
        }
    }
    #pragma unroll
    for (int kt = 0; kt < KT; ++kt) {
        const int k0 = kt * 32 + q * 8;
        short8 bh[NPT], bl[NPT];
        #pragma unroll
        for (int j = 0; j < NPT; ++j) {
            const int p = (pt0t + j) * 16 + n16;
            const int e = p * LDC + (k0 ^ ((p & 7) << 3));
            bh[j] = *(const short8*)(xh + e);
            bl[j] = *(const short8*)(xl + e);
        }
        #pragma unroll
        for (int i = 0; i < NOT; ++i) {
            const size_t we = (size_t)((ot0 + i) * 16 + n16) * LDW + kwoff + k0;
            const short8 ah = *(const short8*)(wh + we);
            const short8 al = *(const short8*)(wl + we);
            #pragma unroll
            for (int j = 0; j < NPT; ++j) {
                acc[i][j] = __builtin_amdgcn_mfma_f32_16x16x32_bf16(ah, bh[j], acc[i][j], 0, 0, 0);
                acc[i][j] = __builtin_amdgcn_mfma_f32_16x16x32_bf16(ah, bl[j], acc[i][j], 0, 0, 0);
                acc[i][j] = __builtin_amdgcn_mfma_f32_16x16x32_bf16(al, bh[j], acc[i][j], 0, 0, 0);
            }
        }
    }
}

template<int NOT, int NPT, bool GATE, int LDCO>
__device__ __forceinline__ void store_act(
    f32x4 (&acc)[NOT][NPT], short* __restrict__ oh, short* __restrict__ ol,
    const short* __restrict__ nfh, const short* __restrict__ nfl,
    int ot0, int pt0t, int lane)
{
    const int q = lane >> 4, n16 = lane & 15;
    #pragma unroll
    for (int i = 0; i < NOT; ++i) {
        const int ob = (ot0 + i) * 16 + 4 * q;
        #pragma unroll
        for (int j = 0; j < NPT; ++j) {
            const int p = (pt0t + j) * 16 + n16;
            const int cs = ob ^ ((p & 7) << 3);
            float v[4];
            #pragma unroll
            for (int r = 0; r < 4; ++r) v[r] = acc[i][j][r];
            if (GATE) {
                const short4 h4 = *(const short4*)(nfh + p * 128 + cs);
                const short4 l4 = *(const short4*)(nfl + p * 128 + cs);
                #pragma unroll
                for (int r = 0; r < 4; ++r) {
                    const float base = bf2f((unsigned short)h4[r]) + bf2f((unsigned short)l4[r]);
                    v[r] = fmaf(base, v[r], base);      // base*(1+w)
                }
            } else {
                #pragma unroll
                for (int r = 0; r < 4; ++r) v[r] = fmaxf(v[r], 0.f);
            }
            short4 h4o, l4o;
            #pragma unroll
            for (int r = 0; r < 4; ++r) {
                const unsigned short h = f2bf(v[r]);
                h4o[r] = (short)h;
                l4o[r] = (short)f2bf(v[r] - bf2f(h));
            }
            *(short4*)(oh + p * LDCO + cs) = h4o;
            *(short4*)(ol + p * LDCO + cs) = l4o;
        }
    }
}

template<bool DENSE>
__global__ __launch_bounds__(512, 3) void pointnet_sa(
    const float* __restrict__ xyz, const float* __restrict__ features,
    const float* __restrict__ new_xyz, const int* __restrict__ idx,
    const short* __restrict__ ws, const short* __restrict__ ftH, const short* __restrict__ ftL,
    const float* __restrict__ bg, const float* __restrict__ b1,
    const float* __restrict__ b2, const float* __restrict__ b3,
    float* __restrict__ out_pooled)  // (B, 256, P)
{
    __shared__ alignas(16) short smem[24576];      // 48 KB
    short* NFh = smem;                              // [64][128]
    short* NFl = smem + 8192;
    short* X0h = smem + 16384;                      // [64][64]
    short* X0l = smem + 20480;
    // X1  = NF cols 0-63   (stride 128)  — NF dead after stage g
    // X2P = X0 region, cols 0-63 (stride 64); X2Q = NF cols 64-127 (stride 128)

    const int tid = threadIdx.x, lane = tid & 63, wave = tid >> 6;
    const int q = lane >> 4, n16 = lane & 15;
    const int pt0 = blockIdx.x * 64;
    const int b = pt0 >> 16;                        // P*S = 65536 points per batch

    if (DENSE) {
        // ---- dense gather: 8 threads/point, 4x uint4 load + 4x swizzled b128 store ----
        const int gp = tid >> 3, gc = tid & 7;
        const int pt = pt0 + gp;
        const int n = idx[pt];
        const short* rH = ftH + ((size_t)b * kN + n) * 128;
        const short* rL = ftL + ((size_t)b * kN + n) * 128;
        uint4 hc0 = *(const uint4*)(rH + gc * 8);
        uint4 hc1 = *(const uint4*)(rH + gc * 8 + 64);
        uint4 lc0 = *(const uint4*)(rL + gc * 8);
        uint4 lc1 = *(const uint4*)(rL + gc * 8 + 64);
        if (gc == 0) {                              // merge xyz-diff into cols 0..2
            const float* xp = xyz + ((size_t)b * kN + n) * 3;
            const int pp = (pt >> 5) & (kP - 1);
            const float* np = new_xyz + ((size_t)b * kP + pp) * 3;
            union { uint4 u; short s[8]; } H, L;
            H.u = hc0; L.u = lc0;
            #pragma unroll
            for (int c = 0; c < 3; ++c) {
                const float v = xp[c] - np[c];
                const unsigned short hh = f2bf(v);
                H.s[c] = (short)hh;
                L.s[c] = (short)f2bf(v - bf2f(hh));
            }
            hc0 = H.u; lc0 = L.u;
        }
        const int sw = (gc ^ (gp & 7)) * 8;         // chunk-level XOR swizzle
        *(uint4*)(NFh + gp * 128 + sw)      = hc0;
        *(uint4*)(NFh + gp * 128 + sw + 64) = hc1;
        *(uint4*)(NFl + gp * 128 + sw)      = lc0;
        *(uint4*)(NFl + gp * 128 + sw + 64) = lc1;
    } else {
        // ---- fallback: scalar gather ----
        const int p = tid & 63;
        const int cg = tid >> 6;
        const int pt = pt0 + p;
        const int n = idx[pt];
        const int pp = (pt >> 5) & (kP - 1);
        const float* fbp = features + (size_t)b * kC * kN + n;
        const float* xp = xyz + ((size_t)b * kN + n) * 3;
        const float* np = new_xyz + ((size_t)b * kP + pp) * 3;
        for (int c = cg; c < 128; c += 8) {
            float v;
            if (c < 3)        v = xp[c] - np[c];
            else if (c < 106) v = fbp[(size_t)(c - 3) * kN];
            else              v = 0.f;
            const unsigned short h = f2bf(v);
            const int cs = c ^ ((p & 7) << 3);
            NFh[p * 128 + cs] = (short)h;
            NFl[p * 128 + cs] = (short)f2bf(v - bf2f(h));
        }
    }
    __syncthreads();

    // ---- stage g: w = Wg*nf + bg ; x0 = nf[:64]*(1+w) -> X0 region ----
    {
        f32x4 a[1][2];
        gemm_core<1, 2, 4, 128, 128, true>(NFh, NFl, ws + WG_HI, ws + WG_LO, bg, 0,
                                           wave & 3, 2 * (wave >> 2), lane, a);
        store_act<1, 2, true, 64>(a, X0h, X0l, NFh, NFl, wave & 3, 2 * (wave >> 2), lane);
    }
    __syncthreads();                               // B1: NF dead

    // ---- stage 1: read X0, write X1 into NF cols 0-63 (stride 128) ----
    {
        f32x4 a[1][2];
        gemm_core<1, 2, 2, 64, 64, true>(X0h, X0l, ws + W1_HI, ws + W1_LO, b1, 0,
                                         wave & 3, 2 * (wave >> 2), lane, a);
        store_act<1, 2, false, 128>(a, NFh, NFl, nullptr, nullptr,
                                    wave & 3, 2 * (wave >> 2), lane);
    }
    __syncthreads();                               // B2: X0 dead

    // ---- stage 2: read X1 (NF stride 128, cols<64), write X2 split P/Q ----
    {
        f32x4 a[2][2];
        gemm_core<2, 2, 2, 128, 64, true>(NFh, NFl, ws + W2_HI, ws + W2_LO, b2, 0,
                                          2 * (wave & 3), 2 * (wave >> 2), lane, a);
        if ((wave & 3) < 2)                         // o-tiles 0-3 -> X2P (X0 region)
            store_act<2, 2, false, 64>(a, X0h, X0l, nullptr, nullptr,
                                       2 * (wave & 3), 2 * (wave >> 2), lane);
        else                                        // o-tiles 4-7 -> X2Q (NF cols 64-127)
            store_act<2, 2, false, 128>(a, NFh + 64, NFl + 64, nullptr, nullptr,
                                        (2 * (wave & 3)) & 3, 2 * (wave >> 2), lane);
    }
    __syncthreads();                               // B3

    // ---- stage 3: acc over X2P (k 0-63) then X2Q (k 64-127), + max-pool ----
    {
        f32x4 a[2][4];
        gemm_core<2, 4, 2, 64, 128, true >(X0h, X0l, ws + W3_HI, ws + W3_LO, b3, 0,
                                           2 * wave, 0, lane, a);
        gemm_core<2, 4, 2, 128, 128, false>(NFh + 64, NFl + 64, ws + W3_HI, ws + W3_LO,
                                            nullptr, 64, 2 * wave, 0, lane, a);
        #pragma unroll
        for (int i = 0; i < 2; ++i) {
            #pragma unroll
            for (int sg = 0; sg < 2; ++sg) {
                #pragma unroll
                for (int r = 0; r < 4; ++r) {
                    float v = fmaxf(a[i][2 * sg][r], a[i][2 * sg + 1][r]);
                    v = fmaxf(v, __shfl_xor(v, 1, 16));
                    v = fmaxf(v, __shfl_xor(v, 2, 16));
                    v = fmaxf(v, __shfl_xor(v, 4, 16));
                    v = fmaxf(v, __shfl_xor(v, 8, 16));
                    v = fmaxf(v, 0.f);
                    if (n16 == 0) {
                        const int o = (2 * wave + i) * 16 + 4 * q + r;
                        const int g = (pt0 >> 5) + sg;                 // flat b*P + p
                        out_pooled[((size_t)(g >> 11) * 256 + o) * kP + (g & (kP - 1))] = v;
                    }
                }
            }
        }
    }
}
}  // namespace

extern "C" void kernel_launch(void* const* d_in, const int* in_sizes, int n_in,
                              void* d_out, int out_size, void* d_ws, size_t ws_size,
                              hipStream_t stream) {
    const float* xyz      = (const float*)d_in[0];
    const float* features = (const float*)d_in[1];
    const float* new_xyz  = (const float*)d_in[2];
    const int*   idx      = (const int*)d_in[3];
    const float* Wg = (const float*)d_in[4];
    const float* bg = (const float*)d_in[5];
    const float* W1 = (const float*)d_in[6];
    const float* b1 = (const float*)d_in[7];
    const float* W2 = (const float*)d_in[8];
    const float* b2 = (const float*)d_in[9];
    const float* W3 = (const float*)d_in[10];
    const float* b3 = (const float*)d_in[11];
    float* out = (float*)d_out;
    short* ws  = (short*)d_ws;
    short* ftH = (short*)((char*)d_ws + FT_OFF);
    short* ftL = ftH + FT_SHORTS;

    const int nxyz = kB * kP * 3;
    copy_newxyz<<<(nxyz + 255) / 256, 256, 0, stream>>>(new_xyz, out, nxyz);
    prep_weights<<<(53248 + 255) / 256, 256, 0, stream>>>(Wg, W1, W2, W3, ws);

    float* pooled = out + nxyz;
    if (ws_size >= WS_NEED) {
        prep_feat<<<kB * (kN / 64), 512, 0, stream>>>(features, ftH, ftL);
        pointnet_sa<true><<<(kB * kP * kS) / 64, 512, 0, stream>>>(
            xyz, features, new_xyz, idx, ws, ftH, ftL, bg, b1, b2, b3, pooled);
    } else {
        pointnet_sa<false><<<(kB * kP * kS) / 64, 512, 0, stream>>>(
            xyz, features, new_xyz, idx, ws, nullptr, nullptr, bg, b1, b2, b3, pooled);
    }
}